// Round 4
// baseline (1743.941 us; speedup 1.0000x reference)
//
#include <hip/hip_runtime.h>

#define N_NODES 50000
#define N_EDGES 800000
#define HID 128
#define OUTD 10
#define HOPS 4
#define NGRAPH 128
#define CAP 64
#define OVF_MAX 4096
#define TILE_M 96
#define KC 32
#define EPT 8   // edges per thread in encoder-fused fill (521*192*8 = 800256 >= E)

// ---------- int64-vs-int32 layout probe ----------
__global__ void detect_kernel(const int* __restrict__ ei, int* __restrict__ flag) {
  if (threadIdx.x == 0 && blockIdx.x == 0) {
    int all0 = 1;
    for (int i = 0; i < 64; ++i) {
      if (ei[2 * i + 1] != 0) { all0 = 0; break; }
    }
    flag[0] = all0;
  }
}

__device__ __forceinline__ int ld_idx(const int* p, int i, int is64) {
  return is64 ? p[2 * i] : p[i];
}

__global__ void dinv_kernel(const int* __restrict__ fillcnt, float* __restrict__ dinv) {
  int i = blockIdx.x * blockDim.x + threadIdx.x;
  if (i < N_NODES) dinv[i] = 1.0f / sqrtf(1.0f + (float)fillcnt[i]);
}

// ---------- encoder: CSR fill (atomics) fused with h0 = x @ W_in + b_in ----------
// 96x128 tile, 192 threads, 8x8 register tile (round-3 GEMM body).
__global__ __launch_bounds__(192) void encoder_kernel(const float* __restrict__ A,
                                                      const float* __restrict__ W,
                                                      const float* __restrict__ bias,
                                                      float* __restrict__ C,
                                                      const int* __restrict__ ei,
                                                      int* __restrict__ fillcnt,
                                                      int* __restrict__ col_fixed,
                                                      int* __restrict__ ovf_cnt,
                                                      int* __restrict__ ovf,
                                                      const int* __restrict__ flag) {
  int tid = threadIdx.x;

  // ---- phase 0: edge placement (independent of GEMM; atomics drain under it)
  {
    int is64 = flag[0];
    int base = blockIdx.x * (192 * EPT);
    int dsts[EPT], srcs[EPT], pos[EPT];
#pragma unroll
    for (int u = 0; u < EPT; ++u) {
      int e = base + u * 192 + tid;
      if (e < N_EDGES) {
        dsts[u] = ld_idx(ei, N_EDGES + e, is64);
        srcs[u] = ld_idx(ei, e, is64);
      } else {
        dsts[u] = -1; srcs[u] = 0;
      }
    }
#pragma unroll
    for (int u = 0; u < EPT; ++u)
      pos[u] = (dsts[u] >= 0) ? atomicAdd(&fillcnt[dsts[u]], 1) : 0;
#pragma unroll
    for (int u = 0; u < EPT; ++u) {
      if (dsts[u] >= 0) {
        if (pos[u] < CAP) {
          col_fixed[dsts[u] * CAP + pos[u]] = srcs[u];
        } else {
          int o = atomicAdd(ovf_cnt, 1);
          if (o < OVF_MAX) { ovf[2 * o] = dsts[u]; ovf[2 * o + 1] = srcs[u]; }
        }
      }
    }
  }

  // ---- phase 1: GEMM
  __shared__ float sAt[KC][TILE_M + 4];
  __shared__ float sW2[KC][16][12];
  int row0 = blockIdx.x * TILE_M;
  int tc = tid & 15;
  int tr = tid >> 4;

  float acc[8][8];
#pragma unroll
  for (int i = 0; i < 8; ++i)
#pragma unroll
    for (int j = 0; j < 8; ++j) acc[i][j] = 0.f;

  for (int kc = 0; kc < HID; kc += KC) {
#pragma unroll
    for (int it = 0; it < 4; ++it) {
      int f = it * 192 + tid;
      int r = f >> 3;
      int k4 = (f & 7) << 2;
      int gr = row0 + r;
      float4 v = make_float4(0.f, 0.f, 0.f, 0.f);
      if (gr < N_NODES) v = *(const float4*)(A + (size_t)gr * HID + kc + k4);
      sAt[k4 + 0][r] = v.x;
      sAt[k4 + 1][r] = v.y;
      sAt[k4 + 2][r] = v.z;
      sAt[k4 + 3][r] = v.w;
    }
#pragma unroll
    for (int it = 0; it < 6; ++it) {
      int f = it * 192 + tid;
      if (f < 1024) {
        int k = f >> 5;
        int c4 = (f & 31) << 2;
        float4 v = *(const float4*)(W + (size_t)(kc + k) * HID + c4);
        *(float4*)&sW2[k][c4 >> 3][c4 & 7] = v;
      }
    }
    __syncthreads();

#pragma unroll 2
    for (int k = 0; k < KC; ++k) {
      float4 a0 = *(const float4*)&sAt[k][tr * 8];
      float4 a1 = *(const float4*)&sAt[k][tr * 8 + 4];
      float4 w0 = *(const float4*)&sW2[k][tc][0];
      float4 w1 = *(const float4*)&sW2[k][tc][4];
      float av[8] = {a0.x, a0.y, a0.z, a0.w, a1.x, a1.y, a1.z, a1.w};
      float wv[8] = {w0.x, w0.y, w0.z, w0.w, w1.x, w1.y, w1.z, w1.w};
#pragma unroll
      for (int i = 0; i < 8; ++i)
#pragma unroll
        for (int j = 0; j < 8; ++j) acc[i][j] += av[i] * wv[j];
    }
    __syncthreads();
  }

  float4 bv0 = *(const float4*)(bias + tc * 8);
  float4 bv1 = *(const float4*)(bias + tc * 8 + 4);
#pragma unroll
  for (int i = 0; i < 8; ++i) {
    int gr = row0 + tr * 8 + i;
    if (gr < N_NODES) {
      float4 o0, o1;
      o0.x = acc[i][0] + bv0.x; o0.y = acc[i][1] + bv0.y;
      o0.z = acc[i][2] + bv0.z; o0.w = acc[i][3] + bv0.w;
      o1.x = acc[i][4] + bv1.x; o1.y = acc[i][5] + bv1.y;
      o1.z = acc[i][6] + bv1.z; o1.w = acc[i][7] + bv1.w;
      *(float4*)(C + (size_t)gr * HID + tc * 8) = o0;
      *(float4*)(C + (size_t)gr * HID + tc * 8 + 4) = o1;
    }
  }
}

// ---------- fused hop: g = agg(h) gathered into LDS, then out = relu?(g @ W + b) ----------
// agg(h@W) == agg(h)@W by linearity of the normalized sum.
__global__ __launch_bounds__(192) void hop_kernel(const float* __restrict__ h,
                                                  const int* __restrict__ fillcnt,
                                                  const int* __restrict__ col_fixed,
                                                  const float* __restrict__ dinv,
                                                  const float* __restrict__ W,
                                                  const float* __restrict__ bias,
                                                  const int* __restrict__ ovf_cnt,
                                                  const int* __restrict__ ovf,
                                                  float* __restrict__ out, int relu) {
  __shared__ float sGt[HID][TILE_M + 4];   // transposed gathered tile [k][r]
  __shared__ float sW2[KC][16][12];
  int tid = threadIdx.x;
  int lane = tid & 63;
  int wv = tid >> 6;                        // 0..2, 32 nodes each
  int row0 = blockIdx.x * TILE_M;
  const float2* h2 = (const float2*)h;

  // ---- gather phase: 8-way interleaved node chains per wave
  for (int s0 = 0; s0 < 32; s0 += 8) {
    float2 acc[8];
    int cidx[8]; float cw[8]; int deg[8]; int m[8]; float di[8];
    int mm = 0;
#pragma unroll
    for (int q = 0; q < 8; ++q) {
      int nd = row0 + wv * 32 + s0 + q;
      acc[q] = make_float2(0.f, 0.f);
      deg[q] = 0; di[q] = 0.f;
      if (nd < N_NODES) {
        di[q] = dinv[nd];
        deg[q] = fillcnt[nd];
        float2 v = h2[(size_t)nd * 64 + lane];
        float sn = di[q] * di[q];
        acc[q].x = v.x * sn; acc[q].y = v.y * sn;
      }
      m[q] = min(deg[q], CAP);
      cidx[q] = 0; cw[q] = 0.f;
      if (lane < m[q]) {
        cidx[q] = col_fixed[(row0 + wv * 32 + s0 + q) * CAP + lane];
        cw[q] = dinv[cidx[q]];
      }
      mm = max(mm, m[q]);
    }
    for (int j = 0; j < mm; ++j) {
#pragma unroll
      for (int q = 0; q < 8; ++q) {
        if (j < m[q]) {
          int src = __builtin_amdgcn_readlane(cidx[q], j);
          float w = __uint_as_float((unsigned)__builtin_amdgcn_readlane((int)__float_as_uint(cw[q]), j)) * di[q];
          float2 u = h2[(size_t)src * 64 + lane];
          acc[q].x += u.x * w;
          acc[q].y += u.y * w;
        }
      }
    }
#pragma unroll
    for (int q = 0; q < 8; ++q) {
      if (deg[q] > CAP) {   // rare overflow fixup
        int nd = row0 + wv * 32 + s0 + q;
        int novf = min(*ovf_cnt, OVF_MAX);
        for (int o = 0; o < novf; ++o) {
          if (ovf[2 * o] == nd) {
            int src = ovf[2 * o + 1];
            float w = dinv[src] * di[q];
            float2 u = h2[(size_t)src * 64 + lane];
            acc[q].x += u.x * w;
            acc[q].y += u.y * w;
          }
        }
      }
    }
#pragma unroll
    for (int q = 0; q < 8; ++q) {
      int r = wv * 32 + s0 + q;
      sGt[2 * lane][r] = acc[q].x;
      sGt[2 * lane + 1][r] = acc[q].y;
    }
  }
  __syncthreads();

  // ---- GEMM phase
  int tc = tid & 15;
  int tr = tid >> 4;
  float acc[8][8];
#pragma unroll
  for (int i = 0; i < 8; ++i)
#pragma unroll
    for (int j = 0; j < 8; ++j) acc[i][j] = 0.f;

  for (int kc = 0; kc < HID; kc += KC) {
#pragma unroll
    for (int it = 0; it < 6; ++it) {
      int f = it * 192 + tid;
      if (f < 1024) {
        int k = f >> 5;
        int c4 = (f & 31) << 2;
        float4 v = *(const float4*)(W + (size_t)(kc + k) * HID + c4);
        *(float4*)&sW2[k][c4 >> 3][c4 & 7] = v;
      }
    }
    __syncthreads();
#pragma unroll 2
    for (int k = 0; k < KC; ++k) {
      float4 a0 = *(const float4*)&sGt[kc + k][tr * 8];
      float4 a1 = *(const float4*)&sGt[kc + k][tr * 8 + 4];
      float4 w0 = *(const float4*)&sW2[k][tc][0];
      float4 w1 = *(const float4*)&sW2[k][tc][4];
      float av[8] = {a0.x, a0.y, a0.z, a0.w, a1.x, a1.y, a1.z, a1.w};
      float wv8[8] = {w0.x, w0.y, w0.z, w0.w, w1.x, w1.y, w1.z, w1.w};
#pragma unroll
      for (int i = 0; i < 8; ++i)
#pragma unroll
        for (int j = 0; j < 8; ++j) acc[i][j] += av[i] * wv8[j];
    }
    __syncthreads();
  }

  float4 bv0 = *(const float4*)(bias + tc * 8);
  float4 bv1 = *(const float4*)(bias + tc * 8 + 4);
#pragma unroll
  for (int i = 0; i < 8; ++i) {
    int gr = row0 + tr * 8 + i;
    if (gr < N_NODES) {
      float4 o0, o1;
      o0.x = acc[i][0] + bv0.x; o0.y = acc[i][1] + bv0.y;
      o0.z = acc[i][2] + bv0.z; o0.w = acc[i][3] + bv0.w;
      o1.x = acc[i][4] + bv1.x; o1.y = acc[i][5] + bv1.y;
      o1.z = acc[i][6] + bv1.z; o1.w = acc[i][7] + bv1.w;
      if (relu) {
        o0.x = fmaxf(o0.x, 0.f); o0.y = fmaxf(o0.y, 0.f);
        o0.z = fmaxf(o0.z, 0.f); o0.w = fmaxf(o0.w, 0.f);
        o1.x = fmaxf(o1.x, 0.f); o1.y = fmaxf(o1.y, 0.f);
        o1.z = fmaxf(o1.z, 0.f); o1.w = fmaxf(o1.w, 0.f);
      }
      *(float4*)(out + (size_t)gr * HID + tc * 8) = o0;
      *(float4*)(out + (size_t)gr * HID + tc * 8 + 4) = o1;
    }
  }
}

// ---------- classifier GEMM (128->10) + per-graph pooling; wave-uniform fast path ----------
__global__ __launch_bounds__(256) void pool_kernel(const float* __restrict__ h,
                                                   const float* __restrict__ Wc,
                                                   const float* __restrict__ bc,
                                                   const int* __restrict__ batch,
                                                   float* __restrict__ pool,
                                                   float* __restrict__ cnt, int M,
                                                   const int* __restrict__ flag) {
  __shared__ float sW[HID * OUTD];
  __shared__ float spool[NGRAPH * OUTD];
  __shared__ float scount[NGRAPH];
  int tid = threadIdx.x;
  for (int i = tid; i < HID * OUTD; i += 256) sW[i] = Wc[i];
  for (int i = tid; i < NGRAPH * OUTD; i += 256) spool[i] = 0.f;
  if (tid < NGRAPH) scount[tid] = 0.f;
  __syncthreads();

  int is64 = flag[0];
  int row = blockIdx.x * 256 + tid;
  int rc = min(row, M - 1);
  bool valid = row < M;
  int g = ld_idx(batch, rc, is64);

  float y[OUTD];
#pragma unroll
  for (int o = 0; o < OUTD; ++o) y[o] = bc[o];
  const float4* hr = (const float4*)(h + (size_t)rc * HID);
  for (int k4 = 0; k4 < 32; ++k4) {
    float4 hv = hr[k4];
    int kb = k4 * 4;
#pragma unroll
    for (int o = 0; o < OUTD; ++o) {
      y[o] += hv.x * sW[(kb + 0) * OUTD + o];
      y[o] += hv.y * sW[(kb + 1) * OUTD + o];
      y[o] += hv.z * sW[(kb + 2) * OUTD + o];
      y[o] += hv.w * sW[(kb + 3) * OUTD + o];
    }
  }
  float c = valid ? 1.f : 0.f;
  if (!valid) {
#pragma unroll
    for (int o = 0; o < OUTD; ++o) y[o] = 0.f;
  }

  int g0 = __builtin_amdgcn_readfirstlane(g);
  unsigned long long same = __ballot(g == g0);
  unsigned long long act = __ballot(1);
  if (same == act) {
#pragma unroll
    for (int off = 1; off < 64; off <<= 1) {
#pragma unroll
      for (int o = 0; o < OUTD; ++o) y[o] += __shfl_xor(y[o], off, 64);
      c += __shfl_xor(c, off, 64);
    }
    if ((tid & 63) == 0) {
#pragma unroll
      for (int o = 0; o < OUTD; ++o) atomicAdd(&spool[g0 * OUTD + o], y[o]);
      atomicAdd(&scount[g0], c);
    }
  } else if (valid) {
#pragma unroll
    for (int o = 0; o < OUTD; ++o) atomicAdd(&spool[g * OUTD + o], y[o]);
    atomicAdd(&scount[g], 1.f);
  }
  __syncthreads();
  for (int i = tid; i < NGRAPH * OUTD; i += 256) {
    float v = spool[i];
    if (v != 0.f) atomicAdd(&pool[i], v);
  }
  if (tid < NGRAPH && scount[tid] != 0.f) atomicAdd(&cnt[tid], scount[tid]);
}

__global__ void finalize_kernel(const float* __restrict__ pool,
                                const float* __restrict__ cnt,
                                float* __restrict__ out) {
  int i = blockIdx.x * blockDim.x + threadIdx.x;
  if (i < NGRAPH * OUTD) {
    float c = cnt[i / OUTD];
    out[i] = pool[i] / fmaxf(c, 1.0f);
  }
}

extern "C" void kernel_launch(void* const* d_in, const int* in_sizes, int n_in,
                              void* d_out, int out_size, void* d_ws, size_t ws_size,
                              hipStream_t stream) {
  const float* x      = (const float*)d_in[0];
  const int*   ei     = (const int*)d_in[1];
  const int*   batch  = (const int*)d_in[2];
  const float* W_in   = (const float*)d_in[3];
  const float* b_in   = (const float*)d_in[4];
  const float* W_hops = (const float*)d_in[5];
  const float* b_hops = (const float*)d_in[6];
  const float* W_cls  = (const float*)d_in[7];
  const float* b_cls  = (const float*)d_in[8];
  float* out = (float*)d_out;

  char* ws = (char*)d_ws;
  size_t off = 0;
  auto alloc = [&](size_t bytes) -> void* {
    void* p = ws + off;
    off += (bytes + 255) & ~(size_t)255;
    return p;
  };

  // zero-initialized region first
  int*   fillcnt = (int*)alloc(N_NODES * 4);
  int*   ovf_cnt = (int*)alloc(4);
  float* pool    = (float*)alloc(NGRAPH * OUTD * 4);
  float* cnt     = (float*)alloc(NGRAPH * 4);
  size_t zero_bytes = off;
  int*   flag    = (int*)alloc(4);
  float* dinv    = (float*)alloc(N_NODES * 4);
  int*   ovf     = (int*)alloc(OVF_MAX * 2 * 4);
  int*   col_fixed = (int*)alloc((size_t)N_NODES * CAP * 4);
  float* bufA    = (float*)alloc((size_t)N_NODES * HID * 4);
  float* bufB    = (float*)alloc((size_t)N_NODES * HID * 4);
  (void)ws_size; (void)in_sizes; (void)n_in; (void)out_size;

  hipMemsetAsync(d_ws, 0, zero_bytes, stream);
  detect_kernel<<<1, 64, 0, stream>>>(ei, flag);

  int gblocks = (N_NODES + TILE_M - 1) / TILE_M;   // 521; also covers all edges: 521*192*8 >= E
  encoder_kernel<<<gblocks, 192, 0, stream>>>(x, W_in, b_in, bufA,
                                              ei, fillcnt, col_fixed, ovf_cnt, ovf, flag);
  dinv_kernel<<<(N_NODES + 255) / 256, 256, 0, stream>>>(fillcnt, dinv);

  float* h = bufA;
  float* other = bufB;
  for (int i = 0; i < HOPS; ++i) {
    hop_kernel<<<gblocks, 192, 0, stream>>>(h, fillcnt, col_fixed, dinv,
                                            W_hops + (size_t)i * HID * HID,
                                            b_hops + (size_t)i * HID,
                                            ovf_cnt, ovf, other, (i < HOPS - 1) ? 1 : 0);
    float* t = h; h = other; other = t;
  }

  pool_kernel<<<(N_NODES + 255) / 256, 256, 0, stream>>>(h, W_cls, b_cls, batch, pool, cnt, N_NODES, flag);
  finalize_kernel<<<(NGRAPH * OUTD + 255) / 256, 256, 0, stream>>>(pool, cnt, out);
}

// Round 5
// 536.256 us; speedup vs baseline: 3.2521x; 3.2521x over previous
//
#include <hip/hip_runtime.h>

#define N_NODES 50000
#define N_EDGES 800000
#define HID 128
#define OUTD 10
#define HOPS 4
#define NGRAPH 128
#define CAP 64
#define OVF_MAX 4096
#define GBM 48
#define EPT 3   // edges/thread in encoder fill: 1042 blocks(y==0) * 256 * 3 = 800256 >= E

// ---------- int64-vs-int32 layout probe ----------
__global__ void detect_kernel(const int* __restrict__ ei, int* __restrict__ flag) {
  if (threadIdx.x == 0 && blockIdx.x == 0) {
    int all0 = 1;
    for (int i = 0; i < 64; ++i) {
      if (ei[2 * i + 1] != 0) { all0 = 0; break; }
    }
    flag[0] = all0;
  }
}

__device__ __forceinline__ int ld_idx(const int* p, int i, int is64) {
  return is64 ? p[2 * i] : p[i];
}

__global__ void dinv_kernel(const int* __restrict__ fillcnt, float* __restrict__ dinv) {
  int i = blockIdx.x * blockDim.x + threadIdx.x;
  if (i < N_NODES) dinv[i] = 1.0f / sqrtf(1.0f + (float)fillcnt[i]);
}

// ---------- fold classifier through last (linear) hop: Wf = W4 @ Wc, bf = b4 @ Wc + bc ----------
__global__ void foldw_kernel(const float* __restrict__ W4, const float* __restrict__ Wc,
                             const float* __restrict__ b4, const float* __restrict__ bc,
                             float* __restrict__ Wf, float* __restrict__ bf) {
  int tid = threadIdx.x;
  for (int idx = tid; idx < HID * OUTD; idx += 256) {
    int k = idx / OUTD, o = idx % OUTD;
    float s = 0.f;
    for (int j = 0; j < HID; ++j) s += W4[k * HID + j] * Wc[j * OUTD + o];
    Wf[idx] = s;
  }
  if (tid < OUTD) {
    float s = bc[tid];
    for (int j = 0; j < HID; ++j) s += b4[j] * Wc[j * OUTD + tid];
    bf[tid] = s;
  }
}

// ---------- GEMM body (R2-proven): 48x64 tile, 256 threads, 3x4 per-thread ----------
__device__ __forceinline__ void gemm_body(const float* __restrict__ A,
                                          const float* __restrict__ W,
                                          const float* __restrict__ bias,
                                          float* __restrict__ C, int M,
                                          int row0, int col0) {
  __shared__ float sA[GBM][129];
  __shared__ float sW[128][68];
  int tid = threadIdx.x;

  for (int it = 0; it < 6; ++it) {
    int f = it * 256 + tid;
    int r = f >> 5;
    int k4 = (f & 31) << 2;
    int gr = row0 + r;
    float4 v = make_float4(0.f, 0.f, 0.f, 0.f);
    if (gr < M) v = *(const float4*)(A + (size_t)gr * HID + k4);
    sA[r][k4] = v.x; sA[r][k4 + 1] = v.y; sA[r][k4 + 2] = v.z; sA[r][k4 + 3] = v.w;
  }
  for (int it = 0; it < 8; ++it) {
    int f = it * 256 + tid;
    int k = f >> 4;
    int c4 = (f & 15) << 2;
    *(float4*)&sW[k][c4] = *(const float4*)(W + k * HID + col0 + c4);
  }
  __syncthreads();

  int cg = tid & 15, rg = tid >> 4;
  int rr = rg * 3, cc = cg * 4;
  float acc[3][4];
#pragma unroll
  for (int i = 0; i < 3; ++i)
#pragma unroll
    for (int j = 0; j < 4; ++j) acc[i][j] = 0.f;

#pragma unroll 4
  for (int k = 0; k < 128; ++k) {
    float4 w = *(const float4*)&sW[k][cc];
    float a0 = sA[rr][k], a1 = sA[rr + 1][k], a2 = sA[rr + 2][k];
    acc[0][0] += a0 * w.x; acc[0][1] += a0 * w.y; acc[0][2] += a0 * w.z; acc[0][3] += a0 * w.w;
    acc[1][0] += a1 * w.x; acc[1][1] += a1 * w.y; acc[1][2] += a1 * w.z; acc[1][3] += a1 * w.w;
    acc[2][0] += a2 * w.x; acc[2][1] += a2 * w.y; acc[2][2] += a2 * w.z; acc[2][3] += a2 * w.w;
  }

  float4 bv = make_float4(0.f, 0.f, 0.f, 0.f);
  if (bias) bv = *(const float4*)(bias + col0 + cc);
#pragma unroll
  for (int i = 0; i < 3; ++i) {
    int gr = row0 + rr + i;
    if (gr < M) {
      float4 o;
      o.x = acc[i][0] + bv.x; o.y = acc[i][1] + bv.y;
      o.z = acc[i][2] + bv.z; o.w = acc[i][3] + bv.w;
      *(float4*)(C + (size_t)gr * HID + col0 + cc) = o;
    }
  }
}

__global__ __launch_bounds__(256) void gemm_kernel(const float* __restrict__ A,
                                                   const float* __restrict__ W,
                                                   const float* __restrict__ bias,
                                                   float* __restrict__ C, int M) {
  gemm_body(A, W, bias, C, M, blockIdx.x * GBM, blockIdx.y * 64);
}

// ---------- encoder: CSR fill (atomics, y==0 blocks) fused with h0 = x @ W_in + b_in ----------
__global__ __launch_bounds__(256) void encoder_kernel(const float* __restrict__ A,
                                                      const float* __restrict__ W,
                                                      const float* __restrict__ bias,
                                                      float* __restrict__ C,
                                                      const int* __restrict__ ei,
                                                      int* __restrict__ fillcnt,
                                                      int* __restrict__ col_fixed,
                                                      int* __restrict__ ovf_cnt,
                                                      int* __restrict__ ovf,
                                                      const int* __restrict__ flag) {
  if (blockIdx.y == 0) {
    int is64 = flag[0];
    int tid = threadIdx.x;
    int base = blockIdx.x * (256 * EPT);
    int dsts[EPT], srcs[EPT], pos[EPT];
#pragma unroll
    for (int u = 0; u < EPT; ++u) {
      int e = base + u * 256 + tid;
      if (e < N_EDGES) {
        dsts[u] = ld_idx(ei, N_EDGES + e, is64);
        srcs[u] = ld_idx(ei, e, is64);
      } else {
        dsts[u] = -1; srcs[u] = 0;
      }
    }
#pragma unroll
    for (int u = 0; u < EPT; ++u)
      pos[u] = (dsts[u] >= 0) ? atomicAdd(&fillcnt[dsts[u]], 1) : 0;
#pragma unroll
    for (int u = 0; u < EPT; ++u) {
      if (dsts[u] >= 0) {
        if (pos[u] < CAP) {
          col_fixed[dsts[u] * CAP + pos[u]] = srcs[u];
        } else {
          int o = atomicAdd(ovf_cnt, 1);
          if (o < OVF_MAX) { ovf[2 * o] = dsts[u]; ovf[2 * o + 1] = srcs[u]; }
        }
      }
    }
  }
  gemm_body(A, W, bias, C, N_NODES, blockIdx.x * GBM, blockIdx.y * 64);
}

// ---------- GCN aggregate (gather): out = agg + xw*selfnorm + b, optional relu ----------
__global__ __launch_bounds__(256) void agg_kernel(const float* __restrict__ xw,
                                                  const int* __restrict__ fillcnt,
                                                  const int* __restrict__ col_fixed,
                                                  const float* __restrict__ dinv,
                                                  const float* __restrict__ bias,
                                                  const int* __restrict__ ovf_cnt,
                                                  const int* __restrict__ ovf,
                                                  float* __restrict__ out, int relu) {
  int wave = threadIdx.x >> 6;
  int lane = threadIdx.x & 63;
  int node = blockIdx.x * 4 + wave;
  if (node >= N_NODES) return;

  const float2* xr = (const float2*)xw;
  float di = dinv[node];
  float sn = di * di;
  float2 v = xr[(size_t)node * 64 + lane];
  float2 b = ((const float2*)bias)[lane];
  float2 acc;
  acc.x = v.x * sn + b.x;
  acc.y = v.y * sn + b.y;

  int deg = fillcnt[node];
  int m = min(deg, CAP);
  int cidx = 0;
  float cw = 0.f;
  if (lane < m) {
    cidx = col_fixed[node * CAP + lane];
    cw = dinv[cidx];
  }
  for (int j = 0; j < m; ++j) {
    int src = __builtin_amdgcn_readlane(cidx, j);
    float w = __uint_as_float((unsigned)__builtin_amdgcn_readlane((int)__float_as_uint(cw), j)) * di;
    float2 u = xr[(size_t)src * 64 + lane];
    acc.x += u.x * w;
    acc.y += u.y * w;
  }
  if (deg > CAP) {
    int novf = min(*ovf_cnt, OVF_MAX);
    for (int o = 0; o < novf; ++o) {
      if (ovf[2 * o] == node) {
        int src = ovf[2 * o + 1];
        float w = dinv[src] * di;
        float2 u = xr[(size_t)src * 64 + lane];
        acc.x += u.x * w;
        acc.y += u.y * w;
      }
    }
  }
  if (relu) {
    acc.x = fmaxf(acc.x, 0.f);
    acc.y = fmaxf(acc.y, 0.f);
  }
  ((float2*)out)[(size_t)node * 64 + lane] = acc;
}

// ---------- z = h3 @ Wf  (50000 x 128 @ 128 x 10) ----------
__global__ __launch_bounds__(256) void z_kernel(const float* __restrict__ h,
                                                const float* __restrict__ Wf,
                                                float* __restrict__ z, int M) {
  __shared__ float sW[HID * OUTD];
  int tid = threadIdx.x;
  for (int i = tid; i < HID * OUTD; i += 256) sW[i] = Wf[i];
  __syncthreads();
  int row = blockIdx.x * 256 + tid;
  if (row >= M) return;
  float y[OUTD];
#pragma unroll
  for (int o = 0; o < OUTD; ++o) y[o] = 0.f;
  const float4* hr = (const float4*)(h + (size_t)row * HID);
  for (int k4 = 0; k4 < 32; ++k4) {
    float4 hv = hr[k4];
    int kb = k4 * 4;
#pragma unroll
    for (int o = 0; o < OUTD; ++o) {
      y[o] += hv.x * sW[(kb + 0) * OUTD + o];
      y[o] += hv.y * sW[(kb + 1) * OUTD + o];
      y[o] += hv.z * sW[(kb + 2) * OUTD + o];
      y[o] += hv.w * sW[(kb + 3) * OUTD + o];
    }
  }
#pragma unroll
  for (int o = 0; o < OUTD; ++o) z[(size_t)row * OUTD + o] = y[o];
}

// ---------- last hop in 10-dim + per-graph mean pooling ----------
__global__ __launch_bounds__(256) void agg10_kernel(const float* __restrict__ z,
                                                    const int* __restrict__ fillcnt,
                                                    const int* __restrict__ col_fixed,
                                                    const float* __restrict__ dinv,
                                                    const float* __restrict__ bf,
                                                    const int* __restrict__ ovf_cnt,
                                                    const int* __restrict__ ovf,
                                                    const int* __restrict__ batch,
                                                    float* __restrict__ pool,
                                                    float* __restrict__ cnt,
                                                    const int* __restrict__ flag) {
  __shared__ float spool[NGRAPH * OUTD];
  __shared__ float scount[NGRAPH];
  int tid = threadIdx.x;
  for (int i = tid; i < NGRAPH * OUTD; i += 256) spool[i] = 0.f;
  if (tid < NGRAPH) scount[tid] = 0.f;
  __syncthreads();

  int is64 = flag[0];
  int node = blockIdx.x * 256 + tid;
  bool valid = node < N_NODES;
  int nc = valid ? node : (N_NODES - 1);
  int g = ld_idx(batch, nc, is64);

  float acc[OUTD];
#pragma unroll
  for (int o = 0; o < OUTD; ++o) acc[o] = 0.f;
  float c = 0.f;

  if (valid) {
    float di = dinv[node];
    float sn = di * di;
#pragma unroll
    for (int o = 0; o < OUTD; ++o) acc[o] = z[(size_t)node * OUTD + o] * sn + bf[o];
    c = 1.f;

    int deg = fillcnt[node];
    int m = min(deg, CAP);
    for (int j = 0; j < m; ++j) {
      int src = col_fixed[node * CAP + j];
      float w = dinv[src] * di;
      const float2* zr = (const float2*)(z + (size_t)src * OUTD);
#pragma unroll
      for (int p = 0; p < 5; ++p) {
        float2 u = zr[p];
        acc[2 * p] += u.x * w;
        acc[2 * p + 1] += u.y * w;
      }
    }
    if (deg > CAP) {
      int novf = min(*ovf_cnt, OVF_MAX);
      for (int o = 0; o < novf; ++o) {
        if (ovf[2 * o] == node) {
          int src = ovf[2 * o + 1];
          float w = dinv[src] * di;
#pragma unroll
          for (int q = 0; q < OUTD; ++q) acc[q] += z[(size_t)src * OUTD + q] * w;
        }
      }
    }
  }

  // pooling: wave-uniform fast path (batch sorted)
  int g0 = __builtin_amdgcn_readfirstlane(g);
  unsigned long long same = __ballot(g == g0);
  unsigned long long act = __ballot(1);
  if (same == act) {
#pragma unroll
    for (int off = 1; off < 64; off <<= 1) {
#pragma unroll
      for (int o = 0; o < OUTD; ++o) acc[o] += __shfl_xor(acc[o], off, 64);
      c += __shfl_xor(c, off, 64);
    }
    if ((tid & 63) == 0) {
#pragma unroll
      for (int o = 0; o < OUTD; ++o) atomicAdd(&spool[g0 * OUTD + o], acc[o]);
      atomicAdd(&scount[g0], c);
    }
  } else if (valid) {
#pragma unroll
    for (int o = 0; o < OUTD; ++o) atomicAdd(&spool[g * OUTD + o], acc[o]);
    atomicAdd(&scount[g], 1.f);
  }
  __syncthreads();
  for (int i = tid; i < NGRAPH * OUTD; i += 256) {
    float v = spool[i];
    if (v != 0.f) atomicAdd(&pool[i], v);
  }
  if (tid < NGRAPH && scount[tid] != 0.f) atomicAdd(&cnt[tid], scount[tid]);
}

__global__ void finalize_kernel(const float* __restrict__ pool,
                                const float* __restrict__ cnt,
                                float* __restrict__ out) {
  int i = blockIdx.x * blockDim.x + threadIdx.x;
  if (i < NGRAPH * OUTD) {
    float c = cnt[i / OUTD];
    out[i] = pool[i] / fmaxf(c, 1.0f);
  }
}

extern "C" void kernel_launch(void* const* d_in, const int* in_sizes, int n_in,
                              void* d_out, int out_size, void* d_ws, size_t ws_size,
                              hipStream_t stream) {
  const float* x      = (const float*)d_in[0];
  const int*   ei     = (const int*)d_in[1];
  const int*   batch  = (const int*)d_in[2];
  const float* W_in   = (const float*)d_in[3];
  const float* b_in   = (const float*)d_in[4];
  const float* W_hops = (const float*)d_in[5];
  const float* b_hops = (const float*)d_in[6];
  const float* W_cls  = (const float*)d_in[7];
  const float* b_cls  = (const float*)d_in[8];
  float* out = (float*)d_out;

  char* ws = (char*)d_ws;
  size_t off = 0;
  auto alloc = [&](size_t bytes) -> void* {
    void* p = ws + off;
    off += (bytes + 255) & ~(size_t)255;
    return p;
  };

  // zero-initialized region first
  int*   fillcnt = (int*)alloc(N_NODES * 4);
  int*   ovf_cnt = (int*)alloc(4);
  float* pool    = (float*)alloc(NGRAPH * OUTD * 4);
  float* cnt     = (float*)alloc(NGRAPH * 4);
  size_t zero_bytes = off;
  int*   flag    = (int*)alloc(4);
  float* dinv    = (float*)alloc(N_NODES * 4);
  int*   ovf     = (int*)alloc(OVF_MAX * 2 * 4);
  int*   col_fixed = (int*)alloc((size_t)N_NODES * CAP * 4);
  float* bufA    = (float*)alloc((size_t)N_NODES * HID * 4);  // h
  float* bufB    = (float*)alloc((size_t)N_NODES * HID * 4);  // xw
  float* z       = (float*)alloc((size_t)N_NODES * OUTD * 4);
  float* Wf      = (float*)alloc(HID * OUTD * 4);
  float* bf      = (float*)alloc(16 * 4);
  (void)ws_size; (void)in_sizes; (void)n_in; (void)out_size;

  hipMemsetAsync(d_ws, 0, zero_bytes, stream);
  detect_kernel<<<1, 64, 0, stream>>>(ei, flag);
  foldw_kernel<<<1, 256, 0, stream>>>(W_hops + 3 * (size_t)HID * HID, W_cls,
                                      b_hops + 3 * HID, b_cls, Wf, bf);

  dim3 ggrid((N_NODES + GBM - 1) / GBM, 2);   // 1042 x 2; y==0 blocks also place edges
  encoder_kernel<<<ggrid, 256, 0, stream>>>(x, W_in, b_in, bufA,
                                            ei, fillcnt, col_fixed, ovf_cnt, ovf, flag);
  dinv_kernel<<<(N_NODES + 255) / 256, 256, 0, stream>>>(fillcnt, dinv);

  for (int i = 0; i < 3; ++i) {   // hops 1..3 (all with ReLU)
    gemm_kernel<<<ggrid, 256, 0, stream>>>(bufA, W_hops + (size_t)i * HID * HID, nullptr, bufB, N_NODES);
    agg_kernel<<<(N_NODES + 3) / 4, 256, 0, stream>>>(bufB, fillcnt, col_fixed, dinv,
                                                      b_hops + (size_t)i * HID, ovf_cnt, ovf,
                                                      bufA, 1);
  }

  // hop 4 folded through classifier (no ReLU): z = h3 @ (W4@Wc); y = agg(z) + bf; pool
  int nb = (N_NODES + 255) / 256;
  z_kernel<<<nb, 256, 0, stream>>>(bufA, Wf, z, N_NODES);
  agg10_kernel<<<nb, 256, 0, stream>>>(z, fillcnt, col_fixed, dinv, bf,
                                       ovf_cnt, ovf, batch, pool, cnt, flag);
  finalize_kernel<<<(NGRAPH * OUTD + 255) / 256, 256, 0, stream>>>(pool, cnt, out);
}

// Round 6
// 519.089 us; speedup vs baseline: 3.3596x; 1.0331x over previous
//
#include <hip/hip_runtime.h>

#define N_NODES 50000
#define N_EDGES 800000
#define HID 128
#define OUTD 10
#define HOPS 4
#define NGRAPH 128
#define CAP 64
#define OVF_MAX 4096
#define GBM 48
#define EPT 3   // edges/thread in encoder fill: 1042 blocks(y==0) * 256 * 3 = 800256 >= E

// ---------- int64-vs-int32 layout probe ----------
__global__ void detect_kernel(const int* __restrict__ ei, int* __restrict__ flag) {
  if (threadIdx.x == 0 && blockIdx.x == 0) {
    int all0 = 1;
    for (int i = 0; i < 64; ++i) {
      if (ei[2 * i + 1] != 0) { all0 = 0; break; }
    }
    flag[0] = all0;
  }
}

__device__ __forceinline__ int ld_idx(const int* p, int i, int is64) {
  return is64 ? p[2 * i] : p[i];
}

__global__ void dinv_kernel(const int* __restrict__ fillcnt, float* __restrict__ dinv) {
  int i = blockIdx.x * blockDim.x + threadIdx.x;
  if (i < N_NODES) dinv[i] = 1.0f / sqrtf(1.0f + (float)fillcnt[i]);
}

// ---------- fold classifier through last (linear) hop: Wf = W4 @ Wc, bf = b4 @ Wc + bc ----------
__global__ void foldw_kernel(const float* __restrict__ W4, const float* __restrict__ Wc,
                             const float* __restrict__ b4, const float* __restrict__ bc,
                             float* __restrict__ Wf, float* __restrict__ bf) {
  int tid = threadIdx.x;
  for (int idx = tid; idx < HID * OUTD; idx += 256) {
    int k = idx / OUTD, o = idx % OUTD;
    float s = 0.f;
    for (int j = 0; j < HID; ++j) s += W4[k * HID + j] * Wc[j * OUTD + o];
    Wf[idx] = s;
  }
  if (tid < OUTD) {
    float s = bc[tid];
    for (int j = 0; j < HID; ++j) s += b4[j] * Wc[j * OUTD + tid];
    bf[tid] = s;
  }
}

// ---------- GEMM body v2: W-half in LDS (32 KB, 5 blocks/CU), A direct from global ----------
// 48 rows x 64 cols per block, 256 threads, 3x4 per-thread tile.
__device__ __forceinline__ void gemm_body(const float* __restrict__ A,
                                          const float* __restrict__ W,
                                          const float* __restrict__ bias,
                                          float* __restrict__ C, int M,
                                          int row0, int col0) {
  __shared__ float sW[HID * 64];   // [k][c] row-major, stride 64 -> per-k b128 reads 2-way (free)
  int tid = threadIdx.x;

  // stage W half-tile: 128x64 = 2048 float4, contiguous b128 writes
#pragma unroll
  for (int it = 0; it < 8; ++it) {
    int f = it * 256 + tid;            // 0..2047
    int k = f >> 4;
    int c4 = (f & 15) << 2;
    *(float4*)&sW[k * 64 + c4] = *(const float4*)(W + (size_t)k * HID + col0 + c4);
  }
  __syncthreads();

  int cg = tid & 15, rg = tid >> 4;    // rg 0..15
  int rr = rg * 3, cc = cg * 4;
  int r0 = row0 + rr;
  // clamp row indices for loads (stores guarded separately)
  size_t b0 = (size_t)min(r0, M - 1) * 32;
  size_t b1 = (size_t)min(r0 + 1, M - 1) * 32;
  size_t b2 = (size_t)min(r0 + 2, M - 1) * 32;
  const float4* A4 = (const float4*)A;

  float acc[3][4];
#pragma unroll
  for (int i = 0; i < 3; ++i)
#pragma unroll
    for (int j = 0; j < 4; ++j) acc[i][j] = 0.f;

#pragma unroll 4
  for (int k4 = 0; k4 < 32; ++k4) {
    float4 a0 = A4[b0 + k4];
    float4 a1 = A4[b1 + k4];
    float4 a2 = A4[b2 + k4];
#pragma unroll
    for (int kk = 0; kk < 4; ++kk) {
      float4 w = *(const float4*)&sW[(4 * k4 + kk) * 64 + cc];
      float x0 = (kk == 0) ? a0.x : (kk == 1) ? a0.y : (kk == 2) ? a0.z : a0.w;
      float x1 = (kk == 0) ? a1.x : (kk == 1) ? a1.y : (kk == 2) ? a1.z : a1.w;
      float x2 = (kk == 0) ? a2.x : (kk == 1) ? a2.y : (kk == 2) ? a2.z : a2.w;
      acc[0][0] += x0 * w.x; acc[0][1] += x0 * w.y; acc[0][2] += x0 * w.z; acc[0][3] += x0 * w.w;
      acc[1][0] += x1 * w.x; acc[1][1] += x1 * w.y; acc[1][2] += x1 * w.z; acc[1][3] += x1 * w.w;
      acc[2][0] += x2 * w.x; acc[2][1] += x2 * w.y; acc[2][2] += x2 * w.z; acc[2][3] += x2 * w.w;
    }
  }

  float4 bv = make_float4(0.f, 0.f, 0.f, 0.f);
  if (bias) bv = *(const float4*)(bias + col0 + cc);
#pragma unroll
  for (int i = 0; i < 3; ++i) {
    int gr = r0 + i;
    if (gr < M) {
      float4 o;
      o.x = acc[i][0] + bv.x; o.y = acc[i][1] + bv.y;
      o.z = acc[i][2] + bv.z; o.w = acc[i][3] + bv.w;
      *(float4*)(C + (size_t)gr * HID + col0 + cc) = o;
    }
  }
}

__global__ __launch_bounds__(256) void gemm_kernel(const float* __restrict__ A,
                                                   const float* __restrict__ W,
                                                   const float* __restrict__ bias,
                                                   float* __restrict__ C, int M) {
  gemm_body(A, W, bias, C, M, blockIdx.x * GBM, blockIdx.y * 64);
}

// ---------- encoder: CSR fill (atomics, y==0 blocks) fused with h0 = x @ W_in + b_in ----------
__global__ __launch_bounds__(256) void encoder_kernel(const float* __restrict__ A,
                                                      const float* __restrict__ W,
                                                      const float* __restrict__ bias,
                                                      float* __restrict__ C,
                                                      const int* __restrict__ ei,
                                                      int* __restrict__ fillcnt,
                                                      int* __restrict__ col_fixed,
                                                      int* __restrict__ ovf_cnt,
                                                      int* __restrict__ ovf,
                                                      const int* __restrict__ flag) {
  if (blockIdx.y == 0) {
    int is64 = flag[0];
    int tid = threadIdx.x;
    int base = blockIdx.x * (256 * EPT);
    int dsts[EPT], srcs[EPT], pos[EPT];
#pragma unroll
    for (int u = 0; u < EPT; ++u) {
      int e = base + u * 256 + tid;
      if (e < N_EDGES) {
        dsts[u] = ld_idx(ei, N_EDGES + e, is64);
        srcs[u] = ld_idx(ei, e, is64);
      } else {
        dsts[u] = -1; srcs[u] = 0;
      }
    }
#pragma unroll
    for (int u = 0; u < EPT; ++u)
      pos[u] = (dsts[u] >= 0) ? atomicAdd(&fillcnt[dsts[u]], 1) : 0;
#pragma unroll
    for (int u = 0; u < EPT; ++u) {
      if (dsts[u] >= 0) {
        if (pos[u] < CAP) {
          col_fixed[dsts[u] * CAP + pos[u]] = srcs[u];
        } else {
          int o = atomicAdd(ovf_cnt, 1);
          if (o < OVF_MAX) { ovf[2 * o] = dsts[u]; ovf[2 * o + 1] = srcs[u]; }
        }
      }
    }
  }
  gemm_body(A, W, bias, C, N_NODES, blockIdx.x * GBM, blockIdx.y * 64);
}

// ---------- GCN aggregate (gather): out = agg + xw*selfnorm + b, optional relu ----------
__global__ __launch_bounds__(256) void agg_kernel(const float* __restrict__ xw,
                                                  const int* __restrict__ fillcnt,
                                                  const int* __restrict__ col_fixed,
                                                  const float* __restrict__ dinv,
                                                  const float* __restrict__ bias,
                                                  const int* __restrict__ ovf_cnt,
                                                  const int* __restrict__ ovf,
                                                  float* __restrict__ out, int relu) {
  int wave = threadIdx.x >> 6;
  int lane = threadIdx.x & 63;
  int node = blockIdx.x * 4 + wave;
  if (node >= N_NODES) return;

  const float2* xr = (const float2*)xw;
  float di = dinv[node];
  float sn = di * di;
  float2 v = xr[(size_t)node * 64 + lane];
  float2 b = ((const float2*)bias)[lane];
  float2 acc;
  acc.x = v.x * sn + b.x;
  acc.y = v.y * sn + b.y;

  int deg = fillcnt[node];
  int m = min(deg, CAP);
  int cidx = 0;
  float cw = 0.f;
  if (lane < m) {
    cidx = col_fixed[node * CAP + lane];
    cw = dinv[cidx];
  }
  for (int j = 0; j < m; ++j) {
    int src = __builtin_amdgcn_readlane(cidx, j);
    float w = __uint_as_float((unsigned)__builtin_amdgcn_readlane((int)__float_as_uint(cw), j)) * di;
    float2 u = xr[(size_t)src * 64 + lane];
    acc.x += u.x * w;
    acc.y += u.y * w;
  }
  if (deg > CAP) {
    int novf = min(*ovf_cnt, OVF_MAX);
    for (int o = 0; o < novf; ++o) {
      if (ovf[2 * o] == node) {
        int src = ovf[2 * o + 1];
        float w = dinv[src] * di;
        float2 u = xr[(size_t)src * 64 + lane];
        acc.x += u.x * w;
        acc.y += u.y * w;
      }
    }
  }
  if (relu) {
    acc.x = fmaxf(acc.x, 0.f);
    acc.y = fmaxf(acc.y, 0.f);
  }
  ((float2*)out)[(size_t)node * 64 + lane] = acc;
}

// ---------- z = h3 @ Wf  (50000 x 128 @ 128 x 10) ----------
__global__ __launch_bounds__(256) void z_kernel(const float* __restrict__ h,
                                                const float* __restrict__ Wf,
                                                float* __restrict__ z, int M) {
  __shared__ float sW[HID * OUTD];
  int tid = threadIdx.x;
  for (int i = tid; i < HID * OUTD; i += 256) sW[i] = Wf[i];
  __syncthreads();
  int row = blockIdx.x * 256 + tid;
  if (row >= M) return;
  float y[OUTD];
#pragma unroll
  for (int o = 0; o < OUTD; ++o) y[o] = 0.f;
  const float4* hr = (const float4*)(h + (size_t)row * HID);
  for (int k4 = 0; k4 < 32; ++k4) {
    float4 hv = hr[k4];
    int kb = k4 * 4;
#pragma unroll
    for (int o = 0; o < OUTD; ++o) {
      y[o] += hv.x * sW[(kb + 0) * OUTD + o];
      y[o] += hv.y * sW[(kb + 1) * OUTD + o];
      y[o] += hv.z * sW[(kb + 2) * OUTD + o];
      y[o] += hv.w * sW[(kb + 3) * OUTD + o];
    }
  }
#pragma unroll
  for (int o = 0; o < OUTD; ++o) z[(size_t)row * OUTD + o] = y[o];
}

// ---------- last hop in 10-dim + per-graph mean pooling ----------
__global__ __launch_bounds__(256) void agg10_kernel(const float* __restrict__ z,
                                                    const int* __restrict__ fillcnt,
                                                    const int* __restrict__ col_fixed,
                                                    const float* __restrict__ dinv,
                                                    const float* __restrict__ bf,
                                                    const int* __restrict__ ovf_cnt,
                                                    const int* __restrict__ ovf,
                                                    const int* __restrict__ batch,
                                                    float* __restrict__ pool,
                                                    float* __restrict__ cnt,
                                                    const int* __restrict__ flag) {
  __shared__ float spool[NGRAPH * OUTD];
  __shared__ float scount[NGRAPH];
  int tid = threadIdx.x;
  for (int i = tid; i < NGRAPH * OUTD; i += 256) spool[i] = 0.f;
  if (tid < NGRAPH) scount[tid] = 0.f;
  __syncthreads();

  int is64 = flag[0];
  int node = blockIdx.x * 256 + tid;
  bool valid = node < N_NODES;
  int nc = valid ? node : (N_NODES - 1);
  int g = ld_idx(batch, nc, is64);

  float acc[OUTD];
#pragma unroll
  for (int o = 0; o < OUTD; ++o) acc[o] = 0.f;
  float c = 0.f;

  if (valid) {
    float di = dinv[node];
    float sn = di * di;
#pragma unroll
    for (int o = 0; o < OUTD; ++o) acc[o] = z[(size_t)node * OUTD + o] * sn + bf[o];
    c = 1.f;

    int deg = fillcnt[node];
    int m = min(deg, CAP);
    for (int j = 0; j < m; ++j) {
      int src = col_fixed[node * CAP + j];
      float w = dinv[src] * di;
      const float2* zr = (const float2*)(z + (size_t)src * OUTD);
#pragma unroll
      for (int p = 0; p < 5; ++p) {
        float2 u = zr[p];
        acc[2 * p] += u.x * w;
        acc[2 * p + 1] += u.y * w;
      }
    }
    if (deg > CAP) {
      int novf = min(*ovf_cnt, OVF_MAX);
      for (int o = 0; o < novf; ++o) {
        if (ovf[2 * o] == node) {
          int src = ovf[2 * o + 1];
          float w = dinv[src] * di;
#pragma unroll
          for (int q = 0; q < OUTD; ++q) acc[q] += z[(size_t)src * OUTD + q] * w;
        }
      }
    }
  }

  // pooling: wave-uniform fast path (batch sorted)
  int g0 = __builtin_amdgcn_readfirstlane(g);
  unsigned long long same = __ballot(g == g0);
  unsigned long long act = __ballot(1);
  if (same == act) {
#pragma unroll
    for (int off = 1; off < 64; off <<= 1) {
#pragma unroll
      for (int o = 0; o < OUTD; ++o) acc[o] += __shfl_xor(acc[o], off, 64);
      c += __shfl_xor(c, off, 64);
    }
    if ((tid & 63) == 0) {
#pragma unroll
      for (int o = 0; o < OUTD; ++o) atomicAdd(&spool[g0 * OUTD + o], acc[o]);
      atomicAdd(&scount[g0], c);
    }
  } else if (valid) {
#pragma unroll
    for (int o = 0; o < OUTD; ++o) atomicAdd(&spool[g * OUTD + o], acc[o]);
    atomicAdd(&scount[g], 1.f);
  }
  __syncthreads();
  for (int i = tid; i < NGRAPH * OUTD; i += 256) {
    float v = spool[i];
    if (v != 0.f) atomicAdd(&pool[i], v);
  }
  if (tid < NGRAPH && scount[tid] != 0.f) atomicAdd(&cnt[tid], scount[tid]);
}

__global__ void finalize_kernel(const float* __restrict__ pool,
                                const float* __restrict__ cnt,
                                float* __restrict__ out) {
  int i = blockIdx.x * blockDim.x + threadIdx.x;
  if (i < NGRAPH * OUTD) {
    float c = cnt[i / OUTD];
    out[i] = pool[i] / fmaxf(c, 1.0f);
  }
}

extern "C" void kernel_launch(void* const* d_in, const int* in_sizes, int n_in,
                              void* d_out, int out_size, void* d_ws, size_t ws_size,
                              hipStream_t stream) {
  const float* x      = (const float*)d_in[0];
  const int*   ei     = (const int*)d_in[1];
  const int*   batch  = (const int*)d_in[2];
  const float* W_in   = (const float*)d_in[3];
  const float* b_in   = (const float*)d_in[4];
  const float* W_hops = (const float*)d_in[5];
  const float* b_hops = (const float*)d_in[6];
  const float* W_cls  = (const float*)d_in[7];
  const float* b_cls  = (const float*)d_in[8];
  float* out = (float*)d_out;

  char* ws = (char*)d_ws;
  size_t off = 0;
  auto alloc = [&](size_t bytes) -> void* {
    void* p = ws + off;
    off += (bytes + 255) & ~(size_t)255;
    return p;
  };

  // zero-initialized region first
  int*   fillcnt = (int*)alloc(N_NODES * 4);
  int*   ovf_cnt = (int*)alloc(4);
  float* pool    = (float*)alloc(NGRAPH * OUTD * 4);
  float* cnt     = (float*)alloc(NGRAPH * 4);
  size_t zero_bytes = off;
  int*   flag    = (int*)alloc(4);
  float* dinv    = (float*)alloc(N_NODES * 4);
  int*   ovf     = (int*)alloc(OVF_MAX * 2 * 4);
  int*   col_fixed = (int*)alloc((size_t)N_NODES * CAP * 4);
  float* bufA    = (float*)alloc((size_t)N_NODES * HID * 4);  // h
  float* bufB    = (float*)alloc((size_t)N_NODES * HID * 4);  // xw
  float* z       = (float*)alloc((size_t)N_NODES * OUTD * 4);
  float* Wf      = (float*)alloc(HID * OUTD * 4);
  float* bf      = (float*)alloc(16 * 4);
  (void)ws_size; (void)in_sizes; (void)n_in; (void)out_size;

  hipMemsetAsync(d_ws, 0, zero_bytes, stream);
  detect_kernel<<<1, 64, 0, stream>>>(ei, flag);
  foldw_kernel<<<1, 256, 0, stream>>>(W_hops + 3 * (size_t)HID * HID, W_cls,
                                      b_hops + 3 * HID, b_cls, Wf, bf);

  dim3 ggrid((N_NODES + GBM - 1) / GBM, 2);   // 1042 x 2; y==0 blocks also place edges
  encoder_kernel<<<ggrid, 256, 0, stream>>>(x, W_in, b_in, bufA,
                                            ei, fillcnt, col_fixed, ovf_cnt, ovf, flag);
  dinv_kernel<<<(N_NODES + 255) / 256, 256, 0, stream>>>(fillcnt, dinv);

  for (int i = 0; i < 3; ++i) {   // hops 1..3 (all with ReLU)
    gemm_kernel<<<ggrid, 256, 0, stream>>>(bufA, W_hops + (size_t)i * HID * HID, nullptr, bufB, N_NODES);
    agg_kernel<<<(N_NODES + 3) / 4, 256, 0, stream>>>(bufB, fillcnt, col_fixed, dinv,
                                                      b_hops + (size_t)i * HID, ovf_cnt, ovf,
                                                      bufA, 1);
  }

  // hop 4 folded through classifier (no ReLU): z = h3 @ (W4@Wc); y = agg(z) + bf; pool
  int nb = (N_NODES + 255) / 256;
  z_kernel<<<nb, 256, 0, stream>>>(bufA, Wf, z, N_NODES);
  agg10_kernel<<<nb, 256, 0, stream>>>(z, fillcnt, col_fixed, dinv, bf,
                                       ovf_cnt, ovf, batch, pool, cnt, flag);
  finalize_kernel<<<(NGRAPH * OUTD + 255) / 256, 256, 0, stream>>>(pool, cnt, out);
}